// Round 1
// baseline (493.410 us; speedup 1.0000x reference)
//
#include <hip/hip_runtime.h>
#include <hip/hip_bf16.h>
#include <cmath>

// Problem constants (from reference): B=1024, D=2048, P=16384, TEMP=0.05, MOMENTUM=0.2
constexpr int B_N = 1024;
constexpr int D_N = 2048;
constexpr int P_N = 16384;
constexpr int TILE = 128;
constexpr int BK = 32;
constexpr int NT = P_N / TILE;  // 128 column tiles
#define TEMP_INV 20.0f
#define MOM 0.2f

typedef __attribute__((ext_vector_type(8))) short s8v;    // 8 bf16 (4 VGPRs) MFMA frag
typedef __attribute__((ext_vector_type(4))) short s4v;    // 4 bf16, 8B LDS store
typedef __attribute__((ext_vector_type(4))) float floatx4;

__device__ inline short f2bf(float f) {  // fp32 -> bf16 bits, RNE
    union { float f; unsigned u; } v; v.f = f;
    unsigned r = v.u + 0x7fffu + ((v.u >> 16) & 1u);
    return (short)(r >> 16);
}

// ---------------------------------------------------------------------------
// GEMM (bf16 MFMA) with fused per-tile softmax partials.
// logits[i,p] = 20 * dot(X[i,:], S[p,:]).  Emits per (row, col-tile):
//   part_max[row*NT+bn] = max over 128 cols, part_sum = sum exp(v - max).
// ---------------------------------------------------------------------------
__global__ __launch_bounds__(256) void gemm_softmax_kernel(
    const float* __restrict__ X, const float* __restrict__ S,
    float* __restrict__ part_max, float* __restrict__ part_sum) {
    __shared__ alignas(16) short sA[TILE][BK];
    __shared__ alignas(16) short sB[TILE][BK];
    __shared__ float pmax[2][TILE];
    __shared__ float psum[2][TILE];

    const int t = threadIdx.x;
    const int bn = blockIdx.x;           // 0..127 (P tiles)
    const int bm = blockIdx.y;           // 0..7   (B tiles)
    const int m0 = bm * TILE;
    const int n0 = bn * TILE;

    const int lane = t & 63;
    const int wave = t >> 6;
    const int wm = (wave & 1) * 64;      // wave M offset in tile
    const int wn = (wave >> 1) * 64;     // wave N offset in tile
    const int frow = lane & 15;
    const int fk = (lane >> 4) * 8;      // A/B frag: lane holds k = (lane>>4)*8 .. +8

    floatx4 acc[4][4];
    for (int i = 0; i < 4; i++)
        for (int j = 0; j < 4; j++)
            acc[i][j] = floatx4{0.f, 0.f, 0.f, 0.f};

    const int srow = t >> 3;             // 0..31
    const int scol = (t & 7) * 4;        // 0..28 step 4

    for (int k0 = 0; k0 < D_N; k0 += BK) {
        __syncthreads();
        // Stage A,B tiles: fp32 global -> bf16 LDS (4 passes of 32 rows)
        for (int p = 0; p < 4; p++) {
            int r = srow + p * 32;
            float4 a = *(const float4*)(X + (size_t)(m0 + r) * D_N + k0 + scol);
            float4 b = *(const float4*)(S + (size_t)(n0 + r) * D_N + k0 + scol);
            *(s4v*)&sA[r][scol] = s4v{f2bf(a.x), f2bf(a.y), f2bf(a.z), f2bf(a.w)};
            *(s4v*)&sB[r][scol] = s4v{f2bf(b.x), f2bf(b.y), f2bf(b.z), f2bf(b.w)};
        }
        __syncthreads();
        s8v af[4], bf[4];
        for (int i = 0; i < 4; i++) af[i] = *(const s8v*)&sA[wm + i * 16 + frow][fk];
        for (int j = 0; j < 4; j++) bf[j] = *(const s8v*)&sB[wn + j * 16 + frow][fk];
        for (int i = 0; i < 4; i++)
            for (int j = 0; j < 4; j++)
                acc[i][j] = __builtin_amdgcn_mfma_f32_16x16x32_bf16(af[i], bf[j], acc[i][j], 0, 0, 0);
    }

    // Epilogue: per-row max/sumexp over this block's 128 columns.
    // C/D layout (measured, m89/m91): col = lane&15, row = (lane>>4)*4 + reg.
    float lmax[4][4], lsum[4][4];
    for (int i = 0; i < 4; i++) {
        for (int r = 0; r < 4; r++) {
            float m = -INFINITY;
            for (int j = 0; j < 4; j++) m = fmaxf(m, acc[i][j][r] * TEMP_INV);
            for (int off = 1; off < 16; off <<= 1) m = fmaxf(m, __shfl_xor(m, off));
            float s = 0.f;
            for (int j = 0; j < 4; j++) s += __expf(acc[i][j][r] * TEMP_INV - m);
            for (int off = 1; off < 16; off <<= 1) s += __shfl_xor(s, off);
            lmax[i][r] = m; lsum[i][r] = s;
        }
    }
    if ((lane & 15) == 0) {
        int lg = lane >> 4;
        for (int i = 0; i < 4; i++)
            for (int r = 0; r < 4; r++) {
                int row = wm + i * 16 + lg * 4 + r;
                pmax[wave >> 1][row] = lmax[i][r];
                psum[wave >> 1][row] = lsum[i][r];
            }
    }
    __syncthreads();
    if (t < TILE) {
        float ma = pmax[0][t], mb = pmax[1][t];
        float M = fmaxf(ma, mb);
        float Sv = psum[0][t] * __expf(ma - M) + psum[1][t] * __expf(mb - M);
        int grow = m0 + t;
        part_max[(size_t)grow * NT + bn] = M;
        part_sum[(size_t)grow * NT + bn] = Sv;
    }
}

// Exact fp32 label logit: ll[i] = 20 * dot(X[i,:], S[labels[i],:])
__global__ __launch_bounds__(256) void label_logit_kernel(
    const float* __restrict__ X, const float* __restrict__ S,
    const int* __restrict__ labels, float* __restrict__ ll) {
    int i = blockIdx.x;
    int t = threadIdx.x;
    const float* x = X + (size_t)i * D_N;
    const float* s = S + (size_t)labels[i] * D_N;
    float acc = 0.f;
    for (int k = t; k < D_N; k += 256) acc += x[k] * s[k];
    for (int off = 32; off; off >>= 1) acc += __shfl_xor(acc, off);
    __shared__ float tmp[4];
    if ((t & 63) == 0) tmp[t >> 6] = acc;
    __syncthreads();
    if (t == 0) ll[i] = (tmp[0] + tmp[1] + tmp[2] + tmp[3]) * TEMP_INV;
}

// Combine partials -> per-row LSE -> mean NLL into out[0]
__global__ __launch_bounds__(1024) void loss_kernel(
    const float* __restrict__ part_max, const float* __restrict__ part_sum,
    const float* __restrict__ ll, float* __restrict__ out) {
    int i = threadIdx.x;  // 0..1023 = row
    const float* pm = part_max + (size_t)i * NT;
    const float* ps = part_sum + (size_t)i * NT;
    float M = -INFINITY;
    for (int tt = 0; tt < NT; tt++) M = fmaxf(M, pm[tt]);
    float Sv = 0.f;
    for (int tt = 0; tt < NT; tt++) Sv += ps[tt] * __expf(pm[tt] - M);
    float v = ll[i] - (M + __logf(Sv));
    for (int off = 32; off; off >>= 1) v += __shfl_xor(v, off);
    __shared__ float tmp[16];
    if ((i & 63) == 0) tmp[i >> 6] = v;
    __syncthreads();
    if (i == 0) {
        float total = 0.f;
        for (int w = 0; w < 16; w++) total += tmp[w];
        out[0] = -total / (float)B_N;
    }
}

// Copy storage -> out (scalar: out+1 is only 4B-aligned)
__global__ __launch_bounds__(1024) void copy_kernel(
    const float* __restrict__ src, float* __restrict__ dst, size_t n) {
    size_t i = (size_t)blockIdx.x * blockDim.x + threadIdx.x;
    if (i < n) dst[i] = src[i];
}

// Sequential-semantics EMA update. Block j acts only if j is the FIRST
// occurrence of its label; it applies the full duplicate chain in order.
__global__ __launch_bounds__(256) void update_kernel(
    const float* __restrict__ X, const float* __restrict__ S,
    const int* __restrict__ labels, float* __restrict__ outS) {
    __shared__ int sl[B_N];
    __shared__ unsigned long long mask[16];
    __shared__ float red[4];
    __shared__ int s_found;
    const int j = blockIdx.x;
    const int t = threadIdx.x;
    for (int k = t; k < B_N; k += 256) sl[k] = labels[k];
    if (t == 0) s_found = 0;
    if (t < 16) mask[t] = 0;
    __syncthreads();
    const int l = sl[j];
    for (int q = 0; q < 4; q++) {
        int k = q * 256 + t;
        if (k < j && sl[k] == l) s_found = 1;                  // benign race
        if (k > j && sl[k] == l) atomicOr(&mask[k >> 6], 1ull << (k & 63));
    }
    __syncthreads();
    if (s_found) return;  // uniform: a predecessor owns this chain

    float r[8];
    {
        const float* srow = S + (size_t)l * D_N;
        for (int u = 0; u < 8; u++) r[u] = srow[t + u * 256];
    }
    int k = j;
    while (true) {
        const float* x = X + (size_t)k * D_N;
        float ss = 0.f;
        for (int u = 0; u < 8; u++) {
            r[u] = MOM * r[u] + (1.0f - MOM) * x[t + u * 256];
            ss += r[u] * r[u];
        }
        for (int off = 32; off; off >>= 1) ss += __shfl_xor(ss, off);
        if ((t & 63) == 0) red[t >> 6] = ss;
        __syncthreads();
        ss = red[0] + red[1] + red[2] + red[3];
        __syncthreads();
        float inv = 1.0f / sqrtf(ss);
        for (int u = 0; u < 8; u++) r[u] *= inv;
        // next chain element (all threads see identical LDS -> uniform)
        int next = -1;
        for (int w = 0; w < 16; w++) {
            unsigned long long bits = mask[w];
            if (bits) { next = w * 64 + __builtin_ctzll(bits); break; }
        }
        if (next < 0) break;
        if (t == 0) mask[next >> 6] &= ~(1ull << (next & 63));
        __syncthreads();
        k = next;
    }
    float* orow = outS + (size_t)l * D_N;
    for (int u = 0; u < 8; u++) orow[t + u * 256] = r[u];
}

extern "C" void kernel_launch(void* const* d_in, const int* in_sizes, int n_in,
                              void* d_out, int out_size, void* d_ws, size_t ws_size,
                              hipStream_t stream) {
    const float* X = (const float*)d_in[0];       // (1024, 2048)
    const float* S = (const float*)d_in[1];       // (16384, 2048)
    const int* labels = (const int*)d_in[4];      // abs_proxy_labels (1024)
    float* out = (float*)d_out;                   // [loss, new_storage...]

    float* part_max = (float*)d_ws;                       // 1024*128 f32
    float* part_sum = part_max + (size_t)B_N * NT;        // 1024*128 f32
    float* ll = part_sum + (size_t)B_N * NT;              // 1024 f32

    gemm_softmax_kernel<<<dim3(NT, B_N / TILE), 256, 0, stream>>>(X, S, part_max, part_sum);
    label_logit_kernel<<<B_N, 256, 0, stream>>>(X, S, labels, ll);
    loss_kernel<<<1, 1024, 0, stream>>>(part_max, part_sum, ll, out);
    copy_kernel<<<(int)(((size_t)P_N * D_N + 1023) / 1024), 1024, 0, stream>>>(
        S, out + 1, (size_t)P_N * D_N);
    update_kernel<<<B_N, 256, 0, stream>>>(X, S, labels, out + 1);
}

// Round 2
// 420.683 us; speedup vs baseline: 1.1729x; 1.1729x over previous
//
#include <hip/hip_runtime.h>
#include <hip/hip_bf16.h>
#include <cmath>

// Problem constants: B=1024, D=2048, P=16384, TEMP=0.05, MOMENTUM=0.2
constexpr int B_N = 1024;
constexpr int D_N = 2048;
constexpr int P_N = 16384;
constexpr int TILE = 128;
constexpr int BK = 32;
constexpr int NT = P_N / TILE;  // 128 column tiles
#define TEMP_INV 20.0f
#define MOM 0.2f

typedef __attribute__((ext_vector_type(8))) short s8v;    // 8 bf16 (16B)
typedef __attribute__((ext_vector_type(4))) float floatx4;

__device__ __forceinline__ short f2bf(float f) {  // fp32 -> bf16 bits, RNE
    union { float f; unsigned u; } v; v.f = f;
    unsigned r = v.u + 0x7fffu + ((v.u >> 16) & 1u);
    return (short)(r >> 16);
}

__device__ __forceinline__ void gl_lds16(const void* g, void* l) {
    __builtin_amdgcn_global_load_lds(
        (const __attribute__((address_space(1))) void*)g,
        (__attribute__((address_space(3))) void*)l, 16, 0, 0);
}

// ---------------------------------------------------------------------------
// Convert: S (fp32) -> Sbf, X (fp32) -> Xbf; also zero out[0] for loss atomics.
// Blocks [0, 16384) handle S, [16384, 17408) handle X. 8 elems/thread.
// ---------------------------------------------------------------------------
__global__ __launch_bounds__(256) void convert_kernel(
    const float* __restrict__ X, const float* __restrict__ S,
    short* __restrict__ Xbf, short* __restrict__ Sbf, float* __restrict__ out0) {
    if (blockIdx.x == 0 && threadIdx.x == 0) out0[0] = 0.f;
    const float* src;
    short* dst;
    size_t base;
    if (blockIdx.x < 16384) {
        src = S; dst = Sbf; base = (size_t)blockIdx.x * 2048 + threadIdx.x * 8;
    } else {
        src = X; dst = Xbf; base = (size_t)(blockIdx.x - 16384) * 2048 + threadIdx.x * 8;
    }
    float4 a = *(const float4*)(src + base);
    float4 b = *(const float4*)(src + base + 4);
    s8v o = s8v{f2bf(a.x), f2bf(a.y), f2bf(a.z), f2bf(a.w),
                f2bf(b.x), f2bf(b.y), f2bf(b.z), f2bf(b.w)};
    *(s8v*)(dst + base) = o;
}

// ---------------------------------------------------------------------------
// bf16 MFMA GEMM (m97 structure: global_load_lds width-16 staging) with fused
// per-tile softmax partials. logits[i,p] = 20 * dot(X[i,:], S[p,:]).
// ---------------------------------------------------------------------------
__global__ __launch_bounds__(256) void gemm_softmax_kernel(
    const short* __restrict__ Xbf, const short* __restrict__ Sbf,
    float* __restrict__ part_max, float* __restrict__ part_sum) {
    __shared__ alignas(16) short sA[TILE * BK];   // 8 KB
    __shared__ alignas(16) short sB[TILE * BK];   // 8 KB
    __shared__ float pmax[2][TILE];
    __shared__ float psum[2][TILE];

    const int t = threadIdx.x;
    const int bn = blockIdx.x;           // 0..127 (P tiles)
    const int bm = blockIdx.y;           // 0..7   (B tiles)
    const int m0 = bm * TILE;
    const int n0 = bn * TILE;

    const int lane = t & 63;
    const int wave = t >> 6;
    const int wm = (wave & 1) * 64;
    const int wn = (wave >> 1) * 64;
    const int frow = lane & 15;
    const int fk = (lane >> 4) * 8;

    floatx4 acc[4][4];
    for (int i = 0; i < 4; i++)
        for (int j = 0; j < 4; j++)
            acc[i][j] = floatx4{0.f, 0.f, 0.f, 0.f};

    // Staging chunks: chunk c (16B) covers row c>>2, k-offset (c&3)*8.
    // LDS dest = chunk*16B which equals wave-uniform-base + lane*16 for c=q*256+t.
    const int r0 = t >> 2, ko0 = (t & 3) * 8;          // chunk t
    const int r1 = (t + 256) >> 2, ko1 = (t & 3) * 8;  // chunk t+256

    for (int k0 = 0; k0 < D_N; k0 += BK) {
        __syncthreads();
        gl_lds16(Xbf + (size_t)(m0 + r0) * D_N + k0 + ko0, &sA[t * 8]);
        gl_lds16(Xbf + (size_t)(m0 + r1) * D_N + k0 + ko1, &sA[(t + 256) * 8]);
        gl_lds16(Sbf + (size_t)(n0 + r0) * D_N + k0 + ko0, &sB[t * 8]);
        gl_lds16(Sbf + (size_t)(n0 + r1) * D_N + k0 + ko1, &sB[(t + 256) * 8]);
        __syncthreads();
        s8v af[4], bf[4];
        for (int i = 0; i < 4; i++) af[i] = *(const s8v*)&sA[(wm + i * 16 + frow) * BK + fk];
        for (int j = 0; j < 4; j++) bf[j] = *(const s8v*)&sB[(wn + j * 16 + frow) * BK + fk];
        for (int i = 0; i < 4; i++)
            for (int j = 0; j < 4; j++)
                acc[i][j] = __builtin_amdgcn_mfma_f32_16x16x32_bf16(af[i], bf[j], acc[i][j], 0, 0, 0);
    }

    // Epilogue: per-row max/sumexp over this block's 128 columns.
    // C/D layout: col = lane&15, row = (lane>>4)*4 + reg.
    float lmax[4][4], lsum[4][4];
    for (int i = 0; i < 4; i++) {
        for (int r = 0; r < 4; r++) {
            float m = -INFINITY;
            for (int j = 0; j < 4; j++) m = fmaxf(m, acc[i][j][r] * TEMP_INV);
            for (int off = 1; off < 16; off <<= 1) m = fmaxf(m, __shfl_xor(m, off));
            float s = 0.f;
            for (int j = 0; j < 4; j++) s += __expf(acc[i][j][r] * TEMP_INV - m);
            for (int off = 1; off < 16; off <<= 1) s += __shfl_xor(s, off);
            lmax[i][r] = m; lsum[i][r] = s;
        }
    }
    if ((lane & 15) == 0) {
        int lg = lane >> 4;
        for (int i = 0; i < 4; i++)
            for (int r = 0; r < 4; r++) {
                int row = wm + i * 16 + lg * 4 + r;
                pmax[wave >> 1][row] = lmax[i][r];
                psum[wave >> 1][row] = lsum[i][r];
            }
    }
    __syncthreads();
    if (t < TILE) {
        float ma = pmax[0][t], mb = pmax[1][t];
        float M = fmaxf(ma, mb);
        float Sv = psum[0][t] * __expf(ma - M) + psum[1][t] * __expf(mb - M);
        int grow = m0 + t;
        part_max[(size_t)grow * NT + bn] = M;
        part_sum[(size_t)grow * NT + bn] = Sv;
    }
}

// Exact fp32 label logit: ll[i] = 20 * dot(X[i,:], S[labels[i],:])
__global__ __launch_bounds__(256) void label_logit_kernel(
    const float* __restrict__ X, const float* __restrict__ S,
    const int* __restrict__ labels, float* __restrict__ ll) {
    int i = blockIdx.x;
    int t = threadIdx.x;
    const float4* x = (const float4*)(X + (size_t)i * D_N);
    const float4* s = (const float4*)(S + (size_t)labels[i] * D_N);
    float acc = 0.f;
    for (int k = t; k < D_N / 4; k += 256) {
        float4 a = x[k], b = s[k];
        acc += a.x * b.x + a.y * b.y + a.z * b.z + a.w * b.w;
    }
    for (int off = 32; off; off >>= 1) acc += __shfl_xor(acc, off);
    __shared__ float tmp[4];
    if ((t & 63) == 0) tmp[t >> 6] = acc;
    __syncthreads();
    if (t == 0) ll[i] = (tmp[0] + tmp[1] + tmp[2] + tmp[3]) * TEMP_INV;
}

// Combine partials -> per-row LSE -> mean NLL, atomicAdd into out[0].
// One wave per row; 4 rows/block; 256 blocks.
__global__ __launch_bounds__(256) void loss_kernel(
    const float* __restrict__ part_max, const float* __restrict__ part_sum,
    const float* __restrict__ ll, float* __restrict__ out0) {
    int wave = threadIdx.x >> 6, lane = threadIdx.x & 63;
    int row = blockIdx.x * 4 + wave;
    const float* pm = part_max + (size_t)row * NT;
    const float* ps = part_sum + (size_t)row * NT;
    float m1 = pm[lane], m2 = pm[lane + 64];
    float M = fmaxf(m1, m2);
    for (int off = 32; off; off >>= 1) M = fmaxf(M, __shfl_xor(M, off));
    float Sv = ps[lane] * __expf(m1 - M) + ps[lane + 64] * __expf(m2 - M);
    for (int off = 32; off; off >>= 1) Sv += __shfl_xor(Sv, off);
    float v = ll[row] - (M + __logf(Sv));
    __shared__ float red[4];
    if (lane == 0) red[wave] = v;
    __syncthreads();
    if (threadIdx.x == 0)
        atomicAdd(out0, -(red[0] + red[1] + red[2] + red[3]) * (1.0f / (float)B_N));
}

// Copy storage -> out+1 (dst only 4B-aligned: vector load, scalar stores)
__global__ __launch_bounds__(256) void copy_kernel(
    const float* __restrict__ src, float* __restrict__ dst) {
    size_t i = ((size_t)blockIdx.x * 256 + threadIdx.x) * 4;
    float4 v = *(const float4*)(src + i);
    dst[i] = v.x; dst[i + 1] = v.y; dst[i + 2] = v.z; dst[i + 3] = v.w;
}

// Sequential-semantics EMA update. Block j acts only if j is the FIRST
// occurrence of its label; it applies the full duplicate chain in order.
__global__ __launch_bounds__(256) void update_kernel(
    const float* __restrict__ X, const float* __restrict__ S,
    const int* __restrict__ labels, float* __restrict__ outS) {
    __shared__ int sl[B_N];
    __shared__ unsigned long long mask[16];
    __shared__ float red[4];
    __shared__ int s_found;
    const int j = blockIdx.x;
    const int t = threadIdx.x;
    for (int k = t; k < B_N; k += 256) sl[k] = labels[k];
    if (t == 0) s_found = 0;
    if (t < 16) mask[t] = 0;
    __syncthreads();
    const int l = sl[j];
    for (int q = 0; q < 4; q++) {
        int k = q * 256 + t;
        if (k < j && sl[k] == l) s_found = 1;                  // benign race
        if (k > j && sl[k] == l) atomicOr(&mask[k >> 6], 1ull << (k & 63));
    }
    __syncthreads();
    if (s_found) return;  // uniform: a predecessor owns this chain

    float r[8];
    {
        const float* srow = S + (size_t)l * D_N;
        for (int u = 0; u < 8; u++) r[u] = srow[t + u * 256];
    }
    int k = j;
    while (true) {
        const float* x = X + (size_t)k * D_N;
        float ss = 0.f;
        for (int u = 0; u < 8; u++) {
            r[u] = MOM * r[u] + (1.0f - MOM) * x[t + u * 256];
            ss += r[u] * r[u];
        }
        for (int off = 32; off; off >>= 1) ss += __shfl_xor(ss, off);
        if ((t & 63) == 0) red[t >> 6] = ss;
        __syncthreads();
        ss = red[0] + red[1] + red[2] + red[3];
        __syncthreads();
        float inv = 1.0f / sqrtf(ss);
        for (int u = 0; u < 8; u++) r[u] *= inv;
        int next = -1;
        for (int w = 0; w < 16; w++) {
            unsigned long long bits = mask[w];
            if (bits) { next = w * 64 + __builtin_ctzll(bits); break; }
        }
        if (next < 0) break;
        if (t == 0) mask[next >> 6] &= ~(1ull << (next & 63));
        __syncthreads();
        k = next;
    }
    float* orow = outS + (size_t)l * D_N;
    for (int u = 0; u < 8; u++) orow[t + u * 256] = r[u];
}

extern "C" void kernel_launch(void* const* d_in, const int* in_sizes, int n_in,
                              void* d_out, int out_size, void* d_ws, size_t ws_size,
                              hipStream_t stream) {
    const float* X = (const float*)d_in[0];       // (1024, 2048)
    const float* S = (const float*)d_in[1];       // (16384, 2048)
    const int* labels = (const int*)d_in[4];      // abs_proxy_labels (1024)
    float* out = (float*)d_out;                   // [loss, new_storage...]

    // Scratch lives INSIDE the output storage region (134 MB), which is
    // overwritten by copy/update at the end. out+4 is 16B-aligned.
    short* RB = (short*)(out + 4);
    short* Sbf = RB;                                   // 33,554,432 bf16 (64 MB)
    short* Xbf = RB + (size_t)P_N * D_N;               // 2,097,152 bf16 (4 MB)
    float* part_max = (float*)(Xbf + (size_t)B_N * D_N);  // 16B-aligned
    float* part_sum = part_max + (size_t)B_N * NT;
    float* ll = part_sum + (size_t)B_N * NT;

    convert_kernel<<<17408, 256, 0, stream>>>(X, S, Xbf, Sbf, out);
    gemm_softmax_kernel<<<dim3(NT, B_N / TILE), 256, 0, stream>>>(Xbf, Sbf, part_max, part_sum);
    label_logit_kernel<<<B_N, 256, 0, stream>>>(X, S, labels, ll);
    loss_kernel<<<256, 256, 0, stream>>>(part_max, part_sum, ll, out);
    copy_kernel<<<(int)((size_t)P_N * D_N / 1024), 256, 0, stream>>>(S, out + 1);
    update_kernel<<<B_N, 256, 0, stream>>>(X, S, labels, out + 1);
}

// Round 3
// 419.025 us; speedup vs baseline: 1.1775x; 1.0040x over previous
//
#include <hip/hip_runtime.h>
#include <hip/hip_bf16.h>
#include <cmath>

// Problem constants: B=1024, D=2048, P=16384, TEMP=0.05, MOMENTUM=0.2
constexpr int B_N = 1024;
constexpr int D_N = 2048;
constexpr int P_N = 16384;
constexpr int TILE = 128;
constexpr int BK = 64;           // fp8 K-tile (2 MFMA k-steps per barrier)
constexpr int NT = P_N / TILE;   // 128 column tiles
#define TEMP_INV 20.0f
#define S_SCALE 16.0f            // storage rows pre-scaled into fp8 range
#define LOGIT_SCALE (TEMP_INV / S_SCALE)
#define MOM 0.2f

typedef __attribute__((ext_vector_type(4))) float floatx4;

__device__ __forceinline__ unsigned char f2fp8(float v) {
    return (unsigned char)(__builtin_amdgcn_cvt_pk_fp8_f32(v, v, 0, false) & 0xFF);
}

__device__ __forceinline__ void gl_lds16(const void* g, void* l) {
    __builtin_amdgcn_global_load_lds(
        (const __attribute__((address_space(1))) void*)g,
        (__attribute__((address_space(3))) void*)l, 16, 0, 0);
}

// ---------------------------------------------------------------------------
// Convert: S -> Sf8 (scaled x16), X -> Xf8; zero out[0]; optionally fused
// copy S -> copy_dst (the storage output) when scratch lives in d_ws.
// Blocks [0,16384) = S rows, [16384,17408) = X rows. Stride-256 accesses:
// every load/store instruction is fully coalesced (256B or 64B per wave).
// ---------------------------------------------------------------------------
__global__ __launch_bounds__(256) void convert_kernel(
    const float* __restrict__ X, const float* __restrict__ S,
    unsigned char* __restrict__ Xf8, unsigned char* __restrict__ Sf8,
    float* __restrict__ out0, float* __restrict__ copy_dst) {
    const int t = threadIdx.x;
    if (blockIdx.x == 0 && t == 0) out0[0] = 0.f;
    if (blockIdx.x < 16384) {
        const size_t base = (size_t)blockIdx.x * D_N;
        const float* src = S + base;
        unsigned char* q = Sf8 + base;
        float v[8];
        for (int u = 0; u < 8; u++) v[u] = src[t + u * 256];
        for (int u = 0; u < 8; u++) q[t + u * 256] = f2fp8(v[u] * S_SCALE);
        if (copy_dst) {
            float* dst = copy_dst + base;
            for (int u = 0; u < 8; u++) dst[t + u * 256] = v[u];
        }
    } else {
        const size_t base = (size_t)(blockIdx.x - 16384) * D_N;
        const float* src = X + base;
        unsigned char* q = Xf8 + base;
        for (int u = 0; u < 8; u++) q[t + u * 256] = f2fp8(src[t + u * 256]);
    }
}

// ---------------------------------------------------------------------------
// fp8 MFMA GEMM (m97 structure: global_load_lds width-16 staging, BK=64)
// with fused per-tile softmax partials. logits[i,p] = 20 * dot(X[i], S[p]).
// XCD swizzle: each XCD owns a contiguous 16-tile bn range (~4MB of Sf8 = L2).
// ---------------------------------------------------------------------------
__global__ __launch_bounds__(256) void gemm_softmax_kernel(
    const unsigned char* __restrict__ Xf8, const unsigned char* __restrict__ Sf8,
    float* __restrict__ part_max, float* __restrict__ part_sum) {
    __shared__ alignas(16) unsigned char sA[TILE * BK];   // 8 KB
    __shared__ alignas(16) unsigned char sB[TILE * BK];   // 8 KB
    __shared__ float pmax[2][TILE];
    __shared__ float psum[2][TILE];

    const int t = threadIdx.x;
    // XCD-aware swizzle (blocks round-robin across 8 XCDs):
    const int b = blockIdx.x;
    const int xcd = b & 7;
    const int s = b >> 3;
    const int bm = s >> 4;                 // 0..7, slowest within an XCD
    const int bn = (xcd << 4) | (s & 15);  // 0..127
    const int m0 = bm * TILE;
    const int n0 = bn * TILE;

    const int lane = t & 63;
    const int wave = t >> 6;
    const int wm = (wave & 1) * 64;
    const int wn = (wave >> 1) * 64;
    const int frow = lane & 15;
    const int g8 = (lane >> 4) * 8;        // byte offset of lane's 8 k-elems

    floatx4 acc[4][4];
    for (int i = 0; i < 4; i++)
        for (int j = 0; j < 4; j++)
            acc[i][j] = floatx4{0.f, 0.f, 0.f, 0.f};

    // Staging: tile = 128 rows x 64B = 512 x 16B chunks; chunk c -> row c>>2,
    // byte-off (c&3)*16. Thread t stages chunks t and t+256 of each tile
    // (LDS dest = chunk*16 = wave-uniform base + lane*16, as required).
    const int r0 = t >> 2, r1 = (t + 256) >> 2;
    const int ko = (t & 3) * 16;

    for (int k0 = 0; k0 < D_N; k0 += BK) {
        __syncthreads();
        gl_lds16(Xf8 + (size_t)(m0 + r0) * D_N + k0 + ko, &sA[t * 16]);
        gl_lds16(Xf8 + (size_t)(m0 + r1) * D_N + k0 + ko, &sA[(t + 256) * 16]);
        gl_lds16(Sf8 + (size_t)(n0 + r0) * D_N + k0 + ko, &sB[t * 16]);
        gl_lds16(Sf8 + (size_t)(n0 + r1) * D_N + k0 + ko, &sB[(t + 256) * 16]);
        __syncthreads();
        for (int kk = 0; kk < 2; kk++) {
            long long af[4], bf[4];
            for (int i = 0; i < 4; i++)
                af[i] = *(const long long*)&sA[(wm + i * 16 + frow) * BK + kk * 32 + g8];
            for (int j = 0; j < 4; j++)
                bf[j] = *(const long long*)&sB[(wn + j * 16 + frow) * BK + kk * 32 + g8];
            for (int i = 0; i < 4; i++)
                for (int j = 0; j < 4; j++)
                    acc[i][j] = __builtin_amdgcn_mfma_f32_16x16x32_fp8_fp8(
                        af[i], bf[j], acc[i][j], 0, 0, 0);
        }
    }

    // Epilogue: per-row max/sumexp over this block's 128 columns.
    // C/D layout: col = lane&15, row = (lane>>4)*4 + reg.
    float lmax[4][4], lsum[4][4];
    for (int i = 0; i < 4; i++) {
        for (int r = 0; r < 4; r++) {
            float m = -INFINITY;
            for (int j = 0; j < 4; j++) m = fmaxf(m, acc[i][j][r] * LOGIT_SCALE);
            for (int off = 1; off < 16; off <<= 1) m = fmaxf(m, __shfl_xor(m, off));
            float s2 = 0.f;
            for (int j = 0; j < 4; j++) s2 += __expf(acc[i][j][r] * LOGIT_SCALE - m);
            for (int off = 1; off < 16; off <<= 1) s2 += __shfl_xor(s2, off);
            lmax[i][r] = m; lsum[i][r] = s2;
        }
    }
    if ((lane & 15) == 0) {
        int lg = lane >> 4;
        for (int i = 0; i < 4; i++)
            for (int r = 0; r < 4; r++) {
                int row = wm + i * 16 + lg * 4 + r;
                pmax[wave >> 1][row] = lmax[i][r];
                psum[wave >> 1][row] = lsum[i][r];
            }
    }
    __syncthreads();
    if (t < TILE) {
        float ma = pmax[0][t], mb = pmax[1][t];
        float M = fmaxf(ma, mb);
        float Sv = psum[0][t] * __expf(ma - M) + psum[1][t] * __expf(mb - M);
        int grow = m0 + t;
        part_max[(size_t)grow * NT + bn] = M;
        part_sum[(size_t)grow * NT + bn] = Sv;
    }
}

// ---------------------------------------------------------------------------
// Loss: one wave per row. Exact fp32 label logit (gather-dot) + LSE over the
// 128 tile partials + mean-NLL atomicAdd into out[0].
// ---------------------------------------------------------------------------
__global__ __launch_bounds__(256) void loss_kernel(
    const float* __restrict__ X, const float* __restrict__ S,
    const int* __restrict__ labels,
    const float* __restrict__ part_max, const float* __restrict__ part_sum,
    float* __restrict__ out0) {
    const int wave = threadIdx.x >> 6, lane = threadIdx.x & 63;
    const int row = blockIdx.x * 4 + wave;
    // exact fp32 label logit
    const float4* x4 = (const float4*)(X + (size_t)row * D_N);
    const float4* s4 = (const float4*)(S + (size_t)labels[row] * D_N);
    float acc = 0.f;
    for (int k = lane; k < D_N / 4; k += 64) {
        float4 a = x4[k], bb = s4[k];
        acc += a.x * bb.x + a.y * bb.y + a.z * bb.z + a.w * bb.w;
    }
    for (int off = 32; off; off >>= 1) acc += __shfl_xor(acc, off);
    float ll = acc * TEMP_INV;
    // LSE over 128 partials
    const float* pm = part_max + (size_t)row * NT;
    const float* ps = part_sum + (size_t)row * NT;
    float m1 = pm[lane], m2 = pm[lane + 64];
    float M = fmaxf(m1, m2);
    for (int off = 32; off; off >>= 1) M = fmaxf(M, __shfl_xor(M, off));
    float Sv = ps[lane] * __expf(m1 - M) + ps[lane + 64] * __expf(m2 - M);
    for (int off = 32; off; off >>= 1) Sv += __shfl_xor(Sv, off);
    float v = ll - (M + __logf(Sv));
    __shared__ float red[4];
    if (lane == 0) red[wave] = v;
    __syncthreads();
    if (threadIdx.x == 0)
        atomicAdd(out0, -(red[0] + red[1] + red[2] + red[3]) * (1.0f / (float)B_N));
}

// Fallback copy (scratch-in-out path): fully coalesced stride-256 dwords.
__global__ __launch_bounds__(256) void copy_kernel(
    const float* __restrict__ src, float* __restrict__ dst) {
    const size_t base = (size_t)blockIdx.x * 2048;
    const int t = threadIdx.x;
    for (int u = 0; u < 8; u++) dst[base + t + u * 256] = src[base + t + u * 256];
}

// Sequential-semantics EMA update. Block j acts only if j is the FIRST
// occurrence of its label; it applies the full duplicate chain in order.
__global__ __launch_bounds__(256) void update_kernel(
    const float* __restrict__ X, const float* __restrict__ S,
    const int* __restrict__ labels, float* __restrict__ outS) {
    __shared__ int sl[B_N];
    __shared__ unsigned long long mask[16];
    __shared__ float red[4];
    __shared__ int s_found;
    const int j = blockIdx.x;
    const int t = threadIdx.x;
    for (int k = t; k < B_N; k += 256) sl[k] = labels[k];
    if (t == 0) s_found = 0;
    if (t < 16) mask[t] = 0;
    __syncthreads();
    const int l = sl[j];
    for (int q = 0; q < 4; q++) {
        int k = q * 256 + t;
        if (k < j && sl[k] == l) s_found = 1;                  // benign race
        if (k > j && sl[k] == l) atomicOr(&mask[k >> 6], 1ull << (k & 63));
    }
    __syncthreads();
    if (s_found) return;  // uniform: a predecessor owns this chain

    float r[8];
    {
        const float* srow = S + (size_t)l * D_N;
        for (int u = 0; u < 8; u++) r[u] = srow[t + u * 256];
    }
    int k = j;
    while (true) {
        const float* x = X + (size_t)k * D_N;
        float ss = 0.f;
        for (int u = 0; u < 8; u++) {
            r[u] = MOM * r[u] + (1.0f - MOM) * x[t + u * 256];
            ss += r[u] * r[u];
        }
        for (int off = 32; off; off >>= 1) ss += __shfl_xor(ss, off);
        if ((t & 63) == 0) red[t >> 6] = ss;
        __syncthreads();
        ss = red[0] + red[1] + red[2] + red[3];
        __syncthreads();
        float inv = 1.0f / sqrtf(ss);
        for (int u = 0; u < 8; u++) r[u] *= inv;
        int next = -1;
        for (int w = 0; w < 16; w++) {
            unsigned long long bits = mask[w];
            if (bits) { next = w * 64 + __builtin_ctzll(bits); break; }
        }
        if (next < 0) break;
        if (t == 0) mask[next >> 6] &= ~(1ull << (next & 63));
        __syncthreads();
        k = next;
    }
    float* orow = outS + (size_t)l * D_N;
    for (int u = 0; u < 8; u++) orow[t + u * 256] = r[u];
}

extern "C" void kernel_launch(void* const* d_in, const int* in_sizes, int n_in,
                              void* d_out, int out_size, void* d_ws, size_t ws_size,
                              hipStream_t stream) {
    const float* X = (const float*)d_in[0];       // (1024, 2048)
    const float* S = (const float*)d_in[1];       // (16384, 2048)
    const int* labels = (const int*)d_in[4];      // abs_proxy_labels (1024)
    float* out = (float*)d_out;                   // [loss, new_storage...]

    // Scratch: Sf8 (33.5MB) + Xf8 (2MB) + partials (1MB) = ~36.7 MB.
    const size_t sf8_bytes = (size_t)P_N * D_N;            // 33,554,432
    const size_t xf8_bytes = (size_t)B_N * D_N;            //  2,097,152
    const size_t need = sf8_bytes + xf8_bytes + (size_t)B_N * NT * 8 + 64;
    const bool use_ws = (ws_size >= need);

    unsigned char* scratch = use_ws ? (unsigned char*)d_ws
                                    : (unsigned char*)d_out + 16;
    unsigned char* Sf8 = scratch;
    unsigned char* Xf8 = scratch + sf8_bytes;
    float* part_max = (float*)(Xf8 + xf8_bytes);           // 16B-aligned
    float* part_sum = part_max + (size_t)B_N * NT;

    // Fused path: convert also writes the storage copy (reads S only once).
    convert_kernel<<<17408, 256, 0, stream>>>(X, S, Xf8, Sf8, out,
                                              use_ws ? (out + 1) : nullptr);
    gemm_softmax_kernel<<<1024, 256, 0, stream>>>(Xf8, Sf8, part_max, part_sum);
    loss_kernel<<<256, 256, 0, stream>>>(X, S, labels, part_max, part_sum, out);
    if (!use_ws)  // scratch lived inside out: write storage copy now
        copy_kernel<<<P_N, 256, 0, stream>>>(S, out + 1);
    update_kernel<<<B_N, 256, 0, stream>>>(X, S, labels, out + 1);
}